// Round 1
// baseline (319.622 us; speedup 1.0000x reference)
//
#include <hip/hip_runtime.h>
#include <hip/hip_bf16.h>

#define EMBED 1024
#define NHEADS 16
#define HDIM 64
#define NB 2
#define NSEQ 2048
#define NTOK (NB*NSEQ)   // 4096

using short8  = __attribute__((ext_vector_type(8))) short;
using short4v = __attribute__((ext_vector_type(4))) short;
using f32x4   = __attribute__((ext_vector_type(4))) float;

__device__ __forceinline__ short f2bf(float x) {
  __hip_bfloat16 h = __float2bfloat16(x);
  short s;
  __builtin_memcpy(&s, &h, 2);
  return s;
}

// ---------------- LayerNorm: f32 [4096][1024] -> bf16 xn ----------------
__global__ __launch_bounds__(256) void ln_kernel(const float* __restrict__ x,
    const float* __restrict__ gamma, const float* __restrict__ beta,
    short* __restrict__ xn) {
  const int row = blockIdx.x;
  const int tid = threadIdx.x;
  const float* xr = x + (size_t)row * EMBED;
  float4 v = *(const float4*)(xr + tid * 4);
  float s  = v.x + v.y + v.z + v.w;
  float s2 = v.x*v.x + v.y*v.y + v.z*v.z + v.w*v.w;
#pragma unroll
  for (int off = 32; off; off >>= 1) {
    s  += __shfl_down(s, off);
    s2 += __shfl_down(s2, off);
  }
  __shared__ float red[8];
  const int wv = tid >> 6, ln = tid & 63;
  if (ln == 0) { red[wv] = s; red[4 + wv] = s2; }
  __syncthreads();
  s  = red[0] + red[1] + red[2] + red[3];
  s2 = red[4] + red[5] + red[6] + red[7];
  const float mu  = s * (1.0f / EMBED);
  const float var = s2 * (1.0f / EMBED) - mu * mu;
  const float inv = rsqrtf(var + 1e-5f);
  float4 g  = *(const float4*)(gamma + tid * 4);
  float4 bt = *(const float4*)(beta + tid * 4);
  short4v o;
  o[0] = f2bf((v.x - mu) * inv * g.x + bt.x);
  o[1] = f2bf((v.y - mu) * inv * g.y + bt.y);
  o[2] = f2bf((v.z - mu) * inv * g.z + bt.z);
  o[3] = f2bf((v.w - mu) * inv * g.w + bt.w);
  *(short4v*)(xn + (size_t)row * EMBED + tid * 4) = o;
}

// ---------------- weight cast: 4 x 1M f32 -> bf16 ----------------
__global__ __launch_bounds__(256) void cast4_kernel(
    const float* __restrict__ a, const float* __restrict__ b,
    const float* __restrict__ c, const float* __restrict__ d,
    short* __restrict__ oa, short* __restrict__ ob,
    short* __restrict__ oc, short* __restrict__ od) {
  const int wsel = blockIdx.y;
  const float* s = (wsel == 0) ? a : (wsel == 1) ? b : (wsel == 2) ? c : d;
  short* o       = (wsel == 0) ? oa : (wsel == 1) ? ob : (wsel == 2) ? oc : od;
  const int i = (blockIdx.x * 256 + threadIdx.x) * 4;
  float4 v = *(const float4*)(s + i);
  short4v r;
  r[0] = f2bf(v.x); r[1] = f2bf(v.y); r[2] = f2bf(v.z); r[3] = f2bf(v.w);
  *(short4v*)(o + i) = r;
}

// ---------------- GEMM: C[M][1024] = A[M][1024] @ W^T + bias ----------------
// W is [out=1024][in=1024] row-major (both operands K-contiguous).
// 128x128 tile, BK=32, 4 waves (2x2 of 64x64), mfma 16x16x32 bf16.
template<bool F32OUT>
__global__ __launch_bounds__(256) void gemm_kernel(
    const short* __restrict__ A,
    const short* __restrict__ W0, const short* __restrict__ W1, const short* __restrict__ W2,
    const float* __restrict__ b0, const float* __restrict__ b1, const float* __restrict__ b2,
    void* __restrict__ O0, void* __restrict__ O1, void* __restrict__ O2) {
  constexpr int K = 1024, NOUT = 1024;
  const int z = blockIdx.z;
  const short* Bw   = (z == 0) ? W0 : (z == 1) ? W1 : W2;
  const float* bias = (z == 0) ? b0 : (z == 1) ? b1 : b2;
  void* Cout        = (z == 0) ? O0 : (z == 1) ? O1 : O2;

  const int tn = blockIdx.x, tm = blockIdx.y;
  const int tid = threadIdx.x, w = tid >> 6, lane = tid & 63;
  const int wm = w >> 1, wn = w & 1;
  const int g = lane >> 4, c = lane & 15;

  __shared__ short As[128 * 32];
  __shared__ short Bs[128 * 32];

  f32x4 acc[4][4];
#pragma unroll
  for (int i = 0; i < 4; i++)
#pragma unroll
    for (int j = 0; j < 4; j++) acc[i][j] = (f32x4){0.f, 0.f, 0.f, 0.f};

  const int crow = tid >> 2;   // 0..63
  const int ckc  = tid & 3;    // 0..3 (8-elem k-chunk)
  short8 ra[2], rb[2];

  auto LOADG = [&](int k0) {
#pragma unroll
    for (int i = 0; i < 2; i++) {
      int row = crow + i * 64;
      ra[i] = *(const short8*)(A  + (size_t)(tm * 128 + row) * K + k0 + ckc * 8);
      rb[i] = *(const short8*)(Bw + (size_t)(tn * 128 + row) * K + k0 + ckc * 8);
    }
  };

  LOADG(0);
  for (int k0 = 0; k0 < K; k0 += 32) {
    __syncthreads();
#pragma unroll
    for (int i = 0; i < 2; i++) {
      int row = crow + i * 64;
      *(short8*)&As[row * 32 + ckc * 8] = ra[i];
      *(short8*)&Bs[row * 32 + ckc * 8] = rb[i];
    }
    __syncthreads();
    if (k0 + 32 < K) LOADG(k0 + 32);
    short8 af[4], bfr[4];
#pragma unroll
    for (int mi = 0; mi < 4; mi++)
      af[mi] = *(const short8*)&As[(wm * 64 + mi * 16 + c) * 32 + g * 8];
#pragma unroll
    for (int ni = 0; ni < 4; ni++)
      bfr[ni] = *(const short8*)&Bs[(wn * 64 + ni * 16 + c) * 32 + g * 8];
#pragma unroll
    for (int mi = 0; mi < 4; mi++)
#pragma unroll
      for (int ni = 0; ni < 4; ni++)
        acc[mi][ni] = __builtin_amdgcn_mfma_f32_16x16x32_bf16(af[mi], bfr[ni], acc[mi][ni], 0, 0, 0);
  }

#pragma unroll
  for (int ni = 0; ni < 4; ni++) {
    const int col = tn * 128 + wn * 64 + ni * 16 + c;
    const float bs = bias[col];
#pragma unroll
    for (int mi = 0; mi < 4; mi++) {
#pragma unroll
      for (int j = 0; j < 4; j++) {
        const int row = tm * 128 + wm * 64 + mi * 16 + g * 4 + j;
        const float v = acc[mi][ni][j] + bs;
        if constexpr (F32OUT)
          ((float*)Cout)[(size_t)row * NOUT + col] = v;
        else
          ((short*)Cout)[(size_t)row * NOUT + col] = f2bf(v);
      }
    }
  }
}

// ---------------- Flash attention with causal mask + interpolated rel bias ----------------
// Grid: (32 q-tiles of 64 rows [reversed for load balance], 32 b*h). 4 waves x 16 q-rows.
__global__ __launch_bounds__(256) void attn_kernel(
    const short* __restrict__ Qm, const short* __restrict__ Km, const short* __restrict__ Vm,
    const float* __restrict__ relb, short* __restrict__ ctx) {
  const int qt = 31 - (int)blockIdx.x;
  const int bh = blockIdx.y;
  const int b = bh >> 4, h = bh & 15;
  const int tid = threadIdx.x, w = tid >> 6, lane = tid & 63;
  const int g = lane >> 4, c = lane & 15;

  __shared__ short k_lds[64 * 64];          // swizzled: elem (m,d) at m*64 + (d ^ ((m&7)<<3))
  __shared__ short vt_lds[64 * 64];         // transposed: (d,m) at d*64 + (((m>>3)^(d&7)^(d>>3))<<3 | (m&7))
  __shared__ short p_lds[4][16 * 64];       // per-wave P, swizzled like k_lds
  __shared__ float rrow[64][33];            // bias pre-interpolated along q (padded)

  const int qbase = qt * 64;

  // Pre-interpolate rel bias along the q axis for this block's 64 rows.
  for (int i = tid; i < 64 * 32; i += 256) {
    const int qr = i >> 5, jj = i & 31;
    const int qg = qbase + qr;
    float rv = 0.f;
    if (qg != NSEQ - 1) {
      const float pos = qg * (31.0f / 2047.0f);
      const int i0 = (int)pos;
      const int i1 = min(i0 + 1, 31);
      const float fr = pos - (float)i0;
      const float* T = relb + h * 1024;
      rv = (1.f - fr) * T[i0 * 32 + jj] + fr * T[i1 * 32 + jj];
    }
    rrow[qr][jj] = rv;
  }

  // Q fragments in registers (rows = qbase + w*16 + c, k = d).
  short8 qf[2];
  {
    const short* qp = Qm + (size_t)(b * NSEQ + qbase + w * 16 + c) * EMBED + h * HDIM;
    qf[0] = *(const short8*)(qp + g * 8);
    qf[1] = *(const short8*)(qp + 32 + g * 8);
  }

  float mrow[4], lrow[4];
  f32x4 oacc[4];
#pragma unroll
  for (int j = 0; j < 4; j++) { mrow[j] = -1e30f; lrow[j] = 0.f; }
#pragma unroll
  for (int db = 0; db < 4; db++) oacc[db] = (f32x4){0.f, 0.f, 0.f, 0.f};

  const int stag_row = tid >> 3;        // 0..31 (+32 on second chunk)
  const int stag_d0  = (tid & 7) * 8;
  short8 kr[2], vr[2];
  auto STAGE_LOAD = [&](int kv0) {
#pragma unroll
    for (int i = 0; i < 2; i++) {
      const int row = stag_row + i * 32;
      kr[i] = *(const short8*)(Km + (size_t)(b * NSEQ + kv0 + row) * EMBED + h * HDIM + stag_d0);
      vr[i] = *(const short8*)(Vm + (size_t)(b * NSEQ + kv0 + row) * EMBED + h * HDIM + stag_d0);
    }
  };

  const int nkv = qt + 1;
  STAGE_LOAD(0);
  for (int kt = 0; kt < nkv; kt++) {
    const int kv0 = kt * 64;
    __syncthreads();   // previous tile fully consumed (also: rrow ready)
#pragma unroll
    for (int i = 0; i < 2; i++) {
      const int row = stag_row + i * 32;
      *(short8*)&k_lds[row * 64 + (stag_d0 ^ ((row & 7) << 3))] = kr[i];
      const int xb = (row >> 3) ^ (stag_d0 >> 3);
#pragma unroll
      for (int e = 0; e < 8; e++) {
        const int d = stag_d0 + e;
        vt_lds[d * 64 + (((xb ^ e) << 3) | (row & 7))] = vr[i][e];
      }
    }
    __syncthreads();
    if (kt + 1 < nkv) STAGE_LOAD(kv0 + 64);

    // S = Q K^T  (16 rows x 64 cols per wave)
    f32x4 s[4];
#pragma unroll
    for (int cb = 0; cb < 4; cb++) s[cb] = (f32x4){0.f, 0.f, 0.f, 0.f};
#pragma unroll
    for (int kh = 0; kh < 2; kh++) {
      const int dk = kh * 32 + g * 8;
#pragma unroll
      for (int cb = 0; cb < 4; cb++) {
        const int mcol = cb * 16 + c;
        short8 kf = *(const short8*)&k_lds[mcol * 64 + (dk ^ ((mcol & 7) << 3))];
        s[cb] = __builtin_amdgcn_mfma_f32_16x16x32_bf16(qf[kh], kf, s[cb], 0, 0, 0);
      }
    }

    // scale + rel bias + causal mask + online softmax
    const int qloc = w * 16 + g * 4;   // + j
    float fm[4]; int jm0[4], jm1[4]; bool ml[4];
#pragma unroll
    for (int cb = 0; cb < 4; cb++) {
      const int mg = kv0 + cb * 16 + c;
      const float pos = mg * (31.0f / 2047.0f);
      const int i0 = (int)pos;
      jm0[cb] = i0; jm1[cb] = min(i0 + 1, 31);
      fm[cb] = pos - (float)i0;
      ml[cb] = (mg == NSEQ - 1);
    }
    float pv[4][4];
    float rmax[4];
#pragma unroll
    for (int j = 0; j < 4; j++) rmax[j] = -1e30f;
#pragma unroll
    for (int cb = 0; cb < 4; cb++) {
      const int mg = kv0 + cb * 16 + c;
#pragma unroll
      for (int j = 0; j < 4; j++) {
        const int qg = qbase + qloc + j;
        float sv = s[cb][j] * 0.125f;
        const float rel = ml[cb] ? 0.f
            : (1.f - fm[cb]) * rrow[qloc + j][jm0[cb]] + fm[cb] * rrow[qloc + j][jm1[cb]];
        sv += rel;
        sv = (mg > qg) ? -1e30f : sv;
        pv[cb][j] = sv;
        rmax[j] = fmaxf(rmax[j], sv);
      }
    }
#pragma unroll
    for (int j = 0; j < 4; j++)
#pragma unroll
      for (int off = 1; off < 16; off <<= 1)
        rmax[j] = fmaxf(rmax[j], __shfl_xor(rmax[j], off));
    float alpha[4];
#pragma unroll
    for (int j = 0; j < 4; j++) {
      const float mn = fmaxf(mrow[j], rmax[j]);
      alpha[j] = __expf(mrow[j] - mn);
      mrow[j] = mn;
    }
    float rs[4];
#pragma unroll
    for (int j = 0; j < 4; j++) rs[j] = 0.f;
#pragma unroll
    for (int cb = 0; cb < 4; cb++)
#pragma unroll
      for (int j = 0; j < 4; j++) {
        const float p = __expf(pv[cb][j] - mrow[j]);
        pv[cb][j] = p;
        rs[j] += p;
      }
#pragma unroll
    for (int j = 0; j < 4; j++) {
#pragma unroll
      for (int off = 1; off < 16; off <<= 1)
        rs[j] += __shfl_xor(rs[j], off);
      lrow[j] = lrow[j] * alpha[j] + rs[j];
    }
#pragma unroll
    for (int db = 0; db < 4; db++)
#pragma unroll
      for (int j = 0; j < 4; j++) oacc[db][j] *= alpha[j];

    // P -> LDS (bf16, swizzled), then PV
    short* pw = &p_lds[w][0];
#pragma unroll
    for (int cb = 0; cb < 4; cb++)
#pragma unroll
      for (int j = 0; j < 4; j++) {
        const int prow = g * 4 + j;
        const int pm = cb * 16 + c;
        pw[prow * 64 + (pm ^ ((prow & 7) << 3))] = f2bf(pv[cb][j]);
      }
#pragma unroll
    for (int kb = 0; kb < 2; kb++) {
      const int m0 = kb * 32 + g * 8;
      short8 pa = *(const short8*)&pw[c * 64 + (m0 ^ ((c & 7) << 3))];
      const int mx = m0 >> 3;
#pragma unroll
      for (int db = 0; db < 4; db++) {
        const int d = db * 16 + c;
        short8 vf = *(const short8*)&vt_lds[d * 64 + ((mx ^ (d & 7) ^ (d >> 3)) << 3)];
        oacc[db] = __builtin_amdgcn_mfma_f32_16x16x32_bf16(pa, vf, oacc[db], 0, 0, 0);
      }
    }
  }

  // finalize: O / l -> ctx bf16 [token][h*64+d]
#pragma unroll
  for (int j = 0; j < 4; j++) {
    const float invl = 1.f / lrow[j];
    const int qg = qbase + w * 16 + g * 4 + j;
    short* op = ctx + (size_t)(b * NSEQ + qg) * EMBED + h * HDIM;
#pragma unroll
    for (int db = 0; db < 4; db++)
      op[db * 16 + c] = f2bf(oacc[db][j] * invl);
  }
}

extern "C" void kernel_launch(void* const* d_in, const int* in_sizes, int n_in,
                              void* d_out, int out_size, void* d_ws, size_t ws_size,
                              hipStream_t stream) {
  const float* x     = (const float*)d_in[0];
  const float* Wq    = (const float*)d_in[1];
  const float* bq    = (const float*)d_in[2];
  const float* Wk    = (const float*)d_in[3];
  const float* bk    = (const float*)d_in[4];
  const float* Wv    = (const float*)d_in[5];
  const float* bv    = (const float*)d_in[6];
  const float* Wo    = (const float*)d_in[7];
  const float* bo    = (const float*)d_in[8];
  const float* gamma = (const float*)d_in[9];
  const float* beta  = (const float*)d_in[10];
  const float* relb  = (const float*)d_in[11];
  float* out = (float*)d_out;

  char* ws = (char*)d_ws;
  short* xn  = (short*)ws; ws += (size_t)NTOK * EMBED * 2;
  short* wqb = (short*)ws; ws += (size_t)EMBED * EMBED * 2;
  short* wkb = (short*)ws; ws += (size_t)EMBED * EMBED * 2;
  short* wvb = (short*)ws; ws += (size_t)EMBED * EMBED * 2;
  short* wob = (short*)ws; ws += (size_t)EMBED * EMBED * 2;
  short* qb  = (short*)ws; ws += (size_t)NTOK * EMBED * 2;
  short* kb_ = (short*)ws; ws += (size_t)NTOK * EMBED * 2;
  short* vb_ = (short*)ws; ws += (size_t)NTOK * EMBED * 2;
  short* ctx = (short*)ws; ws += (size_t)NTOK * EMBED * 2;

  ln_kernel<<<dim3(NTOK), dim3(256), 0, stream>>>(x, gamma, beta, xn);
  cast4_kernel<<<dim3(1024, 4), dim3(256), 0, stream>>>(Wq, Wk, Wv, Wo, wqb, wkb, wvb, wob);
  gemm_kernel<false><<<dim3(8, 32, 3), dim3(256), 0, stream>>>(
      xn, wqb, wkb, wvb, bq, bk, bv, (void*)qb, (void*)kb_, (void*)vb_);
  attn_kernel<<<dim3(32, 32), dim3(256), 0, stream>>>(qb, kb_, vb_, relb, ctx);
  gemm_kernel<true><<<dim3(8, 32, 1), dim3(256), 0, stream>>>(
      ctx, wob, wob, wob, bo, bo, bo, (void*)out, (void*)out, (void*)out);
}

// Round 2
// 293.990 us; speedup vs baseline: 1.0872x; 1.0872x over previous
//
#include <hip/hip_runtime.h>
#include <hip/hip_bf16.h>

#define EMBED 1024
#define NHEADS 16
#define HDIM 64
#define NB 2
#define NSEQ 2048
#define NTOK (NB*NSEQ)   // 4096

using short8  = __attribute__((ext_vector_type(8))) short;
using short4v = __attribute__((ext_vector_type(4))) short;
using f32x4   = __attribute__((ext_vector_type(4))) float;

__device__ __forceinline__ short f2bf(float x) {
  __hip_bfloat16 h = __float2bfloat16(x);
  short s;
  __builtin_memcpy(&s, &h, 2);
  return s;
}

#define GLDS16(gp, lp) __builtin_amdgcn_global_load_lds( \
    (const __attribute__((address_space(1))) unsigned int*)(const void*)(gp), \
    (__attribute__((address_space(3))) unsigned int*)(void*)(lp), 16, 0, 0)

// ---------------- LayerNorm: f32 [4096][1024] -> bf16 xn ----------------
__global__ __launch_bounds__(256) void ln_kernel(const float* __restrict__ x,
    const float* __restrict__ gamma, const float* __restrict__ beta,
    short* __restrict__ xn) {
  const int row = blockIdx.x;
  const int tid = threadIdx.x;
  const float* xr = x + (size_t)row * EMBED;
  float4 v = *(const float4*)(xr + tid * 4);
  float s  = v.x + v.y + v.z + v.w;
  float s2 = v.x*v.x + v.y*v.y + v.z*v.z + v.w*v.w;
#pragma unroll
  for (int off = 32; off; off >>= 1) {
    s  += __shfl_down(s, off);
    s2 += __shfl_down(s2, off);
  }
  __shared__ float red[8];
  const int wv = tid >> 6, ln = tid & 63;
  if (ln == 0) { red[wv] = s; red[4 + wv] = s2; }
  __syncthreads();
  s  = red[0] + red[1] + red[2] + red[3];
  s2 = red[4] + red[5] + red[6] + red[7];
  const float mu  = s * (1.0f / EMBED);
  const float var = s2 * (1.0f / EMBED) - mu * mu;
  const float inv = rsqrtf(var + 1e-5f);
  float4 g  = *(const float4*)(gamma + tid * 4);
  float4 bt = *(const float4*)(beta + tid * 4);
  short4v o;
  o[0] = f2bf((v.x - mu) * inv * g.x + bt.x);
  o[1] = f2bf((v.y - mu) * inv * g.y + bt.y);
  o[2] = f2bf((v.z - mu) * inv * g.z + bt.z);
  o[3] = f2bf((v.w - mu) * inv * g.w + bt.w);
  *(short4v*)(xn + (size_t)row * EMBED + tid * 4) = o;
}

// ---------------- weight cast: 4 x 1M f32 -> bf16 ----------------
__global__ __launch_bounds__(256) void cast4_kernel(
    const float* __restrict__ a, const float* __restrict__ b,
    const float* __restrict__ c, const float* __restrict__ d,
    short* __restrict__ oa, short* __restrict__ ob,
    short* __restrict__ oc, short* __restrict__ od) {
  const int wsel = blockIdx.y;
  const float* s = (wsel == 0) ? a : (wsel == 1) ? b : (wsel == 2) ? c : d;
  short* o       = (wsel == 0) ? oa : (wsel == 1) ? ob : (wsel == 2) ? oc : od;
  const int i = (blockIdx.x * 256 + threadIdx.x) * 4;
  float4 v = *(const float4*)(s + i);
  short4v r;
  r[0] = f2bf(v.x); r[1] = f2bf(v.y); r[2] = f2bf(v.z); r[3] = f2bf(v.w);
  *(short4v*)(o + i) = r;
}

// ---------------- GEMM: C[M][1024] = A[M][1024] @ W^T + bias ----------------
// 128x128 tile, BK=32, 4 waves, global_load_lds staging (m97 structure).
template<bool F32OUT>
__global__ __launch_bounds__(256) void gemm_kernel(
    const short* __restrict__ A,
    const short* __restrict__ W0, const short* __restrict__ W1, const short* __restrict__ W2,
    const float* __restrict__ b0, const float* __restrict__ b1, const float* __restrict__ b2,
    void* __restrict__ O0, void* __restrict__ O1, void* __restrict__ O2) {
  constexpr int K = 1024, NOUT = 1024;
  const int z = blockIdx.z;
  const short* Bw   = (z == 0) ? W0 : (z == 1) ? W1 : W2;
  const float* bias = (z == 0) ? b0 : (z == 1) ? b1 : b2;
  void* Cout        = (z == 0) ? O0 : (z == 1) ? O1 : O2;

  const int tn = blockIdx.x, tm = blockIdx.y;
  const int tid = threadIdx.x, w = tid >> 6, lane = tid & 63;
  const int wm = w >> 1, wn = w & 1;
  const int g = lane >> 4, c = lane & 15;

  __shared__ short As[128 * 32];
  __shared__ short Bs[128 * 32];

  f32x4 acc[4][4];
#pragma unroll
  for (int i = 0; i < 4; i++)
#pragma unroll
    for (int j = 0; j < 4; j++) acc[i][j] = (f32x4){0.f, 0.f, 0.f, 0.f};

  const int crow = tid >> 2;   // 0..63
  const int ckc  = tid & 3;    // 0..3
  const short* ga = A  + (size_t)(tm * 128 + crow) * K + ckc * 8;
  const short* gb = Bw + (size_t)(tn * 128 + crow) * K + ckc * 8;
  short* la = &As[tid * 8];
  short* lb = &Bs[tid * 8];

  for (int k0 = 0; k0 < K; k0 += 32) {
    __syncthreads();
    GLDS16(ga + k0, la);
    GLDS16(ga + k0 + (size_t)64 * K, la + 64 * 32);
    GLDS16(gb + k0, lb);
    GLDS16(gb + k0 + (size_t)64 * K, lb + 64 * 32);
    __syncthreads();
    short8 af[4], bfr[4];
#pragma unroll
    for (int mi = 0; mi < 4; mi++)
      af[mi] = *(const short8*)&As[(wm * 64 + mi * 16 + c) * 32 + g * 8];
#pragma unroll
    for (int ni = 0; ni < 4; ni++)
      bfr[ni] = *(const short8*)&Bs[(wn * 64 + ni * 16 + c) * 32 + g * 8];
#pragma unroll
    for (int mi = 0; mi < 4; mi++)
#pragma unroll
      for (int ni = 0; ni < 4; ni++)
        acc[mi][ni] = __builtin_amdgcn_mfma_f32_16x16x32_bf16(af[mi], bfr[ni], acc[mi][ni], 0, 0, 0);
  }

#pragma unroll
  for (int ni = 0; ni < 4; ni++) {
    const int col = tn * 128 + wn * 64 + ni * 16 + c;
    const float bs = bias[col];
#pragma unroll
    for (int mi = 0; mi < 4; mi++) {
#pragma unroll
      for (int j = 0; j < 4; j++) {
        const int row = tm * 128 + wm * 64 + mi * 16 + g * 4 + j;
        const float v = acc[mi][ni][j] + bs;
        if constexpr (F32OUT)
          ((float*)Cout)[(size_t)row * NOUT + col] = v;
        else
          ((short*)Cout)[(size_t)row * NOUT + col] = f2bf(v);
      }
    }
  }
}

// ---------------- Flash attention: swapped QK^T, defer-max, 1 barrier/iter ----------------
// Grid: (32 q-tiles reversed, 32 b*h). 4 waves x 16 q-rows, KVBLK=64, dbuf LDS.
__global__ __launch_bounds__(256) void attn_kernel(
    const short* __restrict__ Qm, const short* __restrict__ Km, const short* __restrict__ Vm,
    const float* __restrict__ relb, short* __restrict__ ctx) {
  const int qt = 31 - (int)blockIdx.x;
  const int bh = blockIdx.y;
  const int b = bh >> 4, h = bh & 15;
  const int tid = threadIdx.x, w = tid >> 6, lane = tid & 63;
  const int g = lane >> 4, c = lane & 15;

  __shared__ short k_lds[2][64 * 64];   // [m][d ^ ((m&7)<<3)]  (via pre-swizzled glds source)
  __shared__ short vt_lds[2][64 * 64];  // transposed: (d,m) at d*64 + (((m>>3)^(d&7)^(d>>3))<<3 | (m&7))
  __shared__ short p_lds[4][16 * 64];   // per-wave P: [q=c][m ^ ((c&7)<<3)]
  __shared__ float rrow[64][33];        // bias pre-interpolated along q

  const int qbase = qt * 64;
  const size_t bhbase = (size_t)b * NSEQ * EMBED + h * HDIM;

  // Q fragments: q-row = qbase + w*16 + c (used as MFMA B-operand)
  short8 qf[2];
  {
    const short* qp = Qm + bhbase + (size_t)(qbase + w * 16 + c) * EMBED;
    qf[0] = *(const short8*)(qp + g * 8);
    qf[1] = *(const short8*)(qp + 32 + g * 8);
  }

  const int srow = tid >> 3;            // 0..31 (+32 second chunk)
  const int sd0  = (tid & 7) * 8;
  const int swz  = (srow & 7) << 3;
  short8 vr[2];

  // ---- prologue: stage tile 0 ----
#pragma unroll
  for (int i = 0; i < 2; i++) {
    const int row = srow + i * 32;
    GLDS16(Km + bhbase + (size_t)row * EMBED + (sd0 ^ swz), &k_lds[0][row * 64 + sd0]);
    vr[i] = *(const short8*)(Vm + bhbase + (size_t)row * EMBED + sd0);
  }
  for (int i = tid; i < 64 * 32; i += 256) {
    const int qr = i >> 5, jj = i & 31;
    const int qg0 = qbase + qr;
    float rv = 0.f;
    if (qg0 != NSEQ - 1) {
      const float pos = qg0 * (31.0f / 2047.0f);
      const int i0 = (int)pos;
      const int i1 = min(i0 + 1, 31);
      const float fr = pos - (float)i0;
      const float* T = relb + h * 1024;
      rv = (1.f - fr) * T[i0 * 32 + jj] + fr * T[i1 * 32 + jj];
    }
    rrow[qr][jj] = rv;
  }
#pragma unroll
  for (int i = 0; i < 2; i++) {
    const int row = srow + i * 32;
    const int xb = (row >> 3) ^ (sd0 >> 3);
#pragma unroll
    for (int e = 0; e < 8; e++) {
      const int d = sd0 + e;
      vt_lds[0][d * 64 + (((xb ^ e) << 3) | (row & 7))] = vr[i][e];
    }
  }
  __syncthreads();

  float mrow = -3.0e38f, lrow = 0.f;
  f32x4 oacc[4];
#pragma unroll
  for (int db = 0; db < 4; db++) oacc[db] = (f32x4){0.f, 0.f, 0.f, 0.f};

  const int qg = qbase + w * 16 + c;
  const float* rr = &rrow[w * 16 + c][0];
  const int csw = (c & 7) << 3;
  const int nkv = qt + 1;

  for (int kt = 0; kt < nkv; kt++) {
    const int cur = kt & 1;
    const int kv0 = kt * 64;
    const short* kl = &k_lds[cur][0];
    const short* vl = &vt_lds[cur][0];

    if (kt + 1 < nkv) {
#pragma unroll
      for (int i = 0; i < 2; i++) {
        const int row = srow + i * 32;
        GLDS16(Km + bhbase + (size_t)(kv0 + 64 + row) * EMBED + (sd0 ^ swz),
               &k_lds[cur ^ 1][row * 64 + sd0]);
        vr[i] = *(const short8*)(Vm + bhbase + (size_t)(kv0 + 64 + row) * EMBED + sd0);
      }
    }

    // S^T = K Q^T : lane (g,c) gets S[q=c][m = mb*16 + g*4 + j]
    f32x4 st[4];
#pragma unroll
    for (int mb = 0; mb < 4; mb++) st[mb] = (f32x4){0.f, 0.f, 0.f, 0.f};
#pragma unroll
    for (int kh = 0; kh < 2; kh++) {
      const int dk = kh * 32 + g * 8;
#pragma unroll
      for (int mb = 0; mb < 4; mb++) {
        const int row = mb * 16 + c;
        short8 kf = *(const short8*)&kl[row * 64 + (dk ^ ((row & 7) << 3))];
        st[mb] = __builtin_amdgcn_mfma_f32_16x16x32_bf16(kf, qf[kh], st[mb], 0, 0, 0);
      }
    }

    // scale + rel bias + causal mask; softmax state is lane-local (row c)
    float p[4][4];
    float pmax = -3.0e38f;
    const bool diag = (kt == qt);
#pragma unroll
    for (int mb = 0; mb < 4; mb++) {
#pragma unroll
      for (int j = 0; j < 4; j++) {
        const int mg = kv0 + mb * 16 + g * 4 + j;
        const float pos = mg * (31.0f / 2047.0f);
        const int i0 = (int)pos;
        const int i1 = min(i0 + 1, 31);
        const float fr = pos - (float)i0;
        float sv = st[mb][j] * 0.125f;
        if (mg != NSEQ - 1) {
          const float r0 = rr[i0];
          sv += r0 + fr * (rr[i1] - r0);
        }
        if (diag && mg > qg) sv = -3.0e38f;
        p[mb][j] = sv;
        pmax = fmaxf(pmax, sv);
      }
    }
    pmax = fmaxf(pmax, __shfl_xor(pmax, 16));
    pmax = fmaxf(pmax, __shfl_xor(pmax, 32));

    if (!__all(pmax - mrow <= 8.0f)) {       // defer-max: rescale only when needed
      const float mnew = fmaxf(mrow, pmax);
      const float al = __expf(mrow - mnew);
      mrow = mnew;
      lrow *= al;
      float alj[4];
#pragma unroll
      for (int j = 0; j < 4; j++) alj[j] = __shfl(al, g * 4 + j);
#pragma unroll
      for (int db = 0; db < 4; db++)
#pragma unroll
        for (int j = 0; j < 4; j++) oacc[db][j] *= alj[j];
    }

    float rs = 0.f;
#pragma unroll
    for (int mb = 0; mb < 4; mb++)
#pragma unroll
      for (int j = 0; j < 4; j++) {
        const float pe = __expf(p[mb][j] - mrow);
        p[mb][j] = pe;
        rs += pe;
      }
    rs += __shfl_xor(rs, 16);
    rs += __shfl_xor(rs, 32);
    lrow += rs;

    // P -> p_lds (bf16 pairs, swizzled), wave-local
    short* pw = &p_lds[w][0];
#pragma unroll
    for (int mb = 0; mb < 4; mb++)
#pragma unroll
      for (int jh = 0; jh < 2; jh++) {
        const int m = mb * 16 + g * 4 + jh * 2;
        unsigned int pk = ((unsigned int)(unsigned short)f2bf(p[mb][jh * 2 + 1]) << 16)
                        |  (unsigned int)(unsigned short)f2bf(p[mb][jh * 2]);
        *(unsigned int*)&pw[c * 64 + (m ^ csw)] = pk;
      }

    // O += P V
#pragma unroll
    for (int kb = 0; kb < 2; kb++) {
      const int m0 = kb * 32 + g * 8;
      short8 pa = *(const short8*)&pw[c * 64 + (m0 ^ csw)];
      const int mx = m0 >> 3;
#pragma unroll
      for (int db = 0; db < 4; db++) {
        const int d = db * 16 + c;
        short8 vf = *(const short8*)&vl[d * 64 + ((mx ^ (d & 7) ^ (d >> 3)) << 3)];
        oacc[db] = __builtin_amdgcn_mfma_f32_16x16x32_bf16(pa, vf, oacc[db], 0, 0, 0);
      }
    }

    // write next V tile into back buffer before the single barrier
    if (kt + 1 < nkv) {
#pragma unroll
      for (int i = 0; i < 2; i++) {
        const int row = srow + i * 32;
        const int xb = (row >> 3) ^ (sd0 >> 3);
#pragma unroll
        for (int e = 0; e < 8; e++) {
          const int d = sd0 + e;
          vt_lds[cur ^ 1][d * 64 + (((xb ^ e) << 3) | (row & 7))] = vr[i][e];
        }
      }
    }
    __syncthreads();
  }

  // epilogue: redistribute l to D-domain rows, normalize, store
  float linv[4];
#pragma unroll
  for (int j = 0; j < 4; j++) linv[j] = 1.f / __shfl(lrow, g * 4 + j);
#pragma unroll
  for (int j = 0; j < 4; j++) {
    short* op = ctx + bhbase + (size_t)(qbase + w * 16 + g * 4 + j) * EMBED;
#pragma unroll
    for (int db = 0; db < 4; db++)
      op[db * 16 + c] = f2bf(oacc[db][j] * linv[j]);
  }
}

extern "C" void kernel_launch(void* const* d_in, const int* in_sizes, int n_in,
                              void* d_out, int out_size, void* d_ws, size_t ws_size,
                              hipStream_t stream) {
  const float* x     = (const float*)d_in[0];
  const float* Wq    = (const float*)d_in[1];
  const float* bq    = (const float*)d_in[2];
  const float* Wk    = (const float*)d_in[3];
  const float* bk    = (const float*)d_in[4];
  const float* Wv    = (const float*)d_in[5];
  const float* bv    = (const float*)d_in[6];
  const float* Wo    = (const float*)d_in[7];
  const float* bo    = (const float*)d_in[8];
  const float* gamma = (const float*)d_in[9];
  const float* beta  = (const float*)d_in[10];
  const float* relb  = (const float*)d_in[11];
  float* out = (float*)d_out;

  char* ws = (char*)d_ws;
  short* xn  = (short*)ws; ws += (size_t)NTOK * EMBED * 2;
  short* wqb = (short*)ws; ws += (size_t)EMBED * EMBED * 2;
  short* wkb = (short*)ws; ws += (size_t)EMBED * EMBED * 2;
  short* wvb = (short*)ws; ws += (size_t)EMBED * EMBED * 2;
  short* wob = (short*)ws; ws += (size_t)EMBED * EMBED * 2;
  short* qb  = (short*)ws; ws += (size_t)NTOK * EMBED * 2;
  short* kb_ = (short*)ws; ws += (size_t)NTOK * EMBED * 2;
  short* vb_ = (short*)ws; ws += (size_t)NTOK * EMBED * 2;
  short* ctx = (short*)ws; ws += (size_t)NTOK * EMBED * 2;

  ln_kernel<<<dim3(NTOK), dim3(256), 0, stream>>>(x, gamma, beta, xn);
  cast4_kernel<<<dim3(1024, 4), dim3(256), 0, stream>>>(Wq, Wk, Wv, Wo, wqb, wkb, wvb, wob);
  gemm_kernel<false><<<dim3(8, 32, 3), dim3(256), 0, stream>>>(
      xn, wqb, wkb, wvb, bq, bk, bv, (void*)qb, (void*)kb_, (void*)vb_);
  attn_kernel<<<dim3(32, 32), dim3(256), 0, stream>>>(qb, kb_, vb_, relb, ctx);
  gemm_kernel<true><<<dim3(8, 32, 1), dim3(256), 0, stream>>>(
      ctx, wob, wob, wob, bo, bo, bo, (void*)out, (void*)out, (void*)out);
}

// Round 3
// 292.631 us; speedup vs baseline: 1.0922x; 1.0046x over previous
//
#include <hip/hip_runtime.h>
#include <hip/hip_bf16.h>

#define EMBED 1024
#define NHEADS 16
#define HDIM 64
#define NB 2
#define NSEQ 2048
#define NTOK (NB*NSEQ)   // 4096

using short8  = __attribute__((ext_vector_type(8))) short;
using short4v = __attribute__((ext_vector_type(4))) short;
using f32x4   = __attribute__((ext_vector_type(4))) float;

__device__ __forceinline__ short f2bf(float x) {
  __hip_bfloat16 h = __float2bfloat16(x);
  short s;
  __builtin_memcpy(&s, &h, 2);
  return s;
}

#define GLDS16(gp, lp) __builtin_amdgcn_global_load_lds( \
    (const __attribute__((address_space(1))) unsigned int*)(const void*)(gp), \
    (__attribute__((address_space(3))) unsigned int*)(void*)(lp), 16, 0, 0)

// ---------------- LayerNorm: f32 [4096][1024] -> bf16 xn ----------------
__global__ __launch_bounds__(256) void ln_kernel(const float* __restrict__ x,
    const float* __restrict__ gamma, const float* __restrict__ beta,
    short* __restrict__ xn) {
  const int row = blockIdx.x;
  const int tid = threadIdx.x;
  const float* xr = x + (size_t)row * EMBED;
  float4 v = *(const float4*)(xr + tid * 4);
  float s  = v.x + v.y + v.z + v.w;
  float s2 = v.x*v.x + v.y*v.y + v.z*v.z + v.w*v.w;
#pragma unroll
  for (int off = 32; off; off >>= 1) {
    s  += __shfl_down(s, off);
    s2 += __shfl_down(s2, off);
  }
  __shared__ float red[8];
  const int wv = tid >> 6, ln = tid & 63;
  if (ln == 0) { red[wv] = s; red[4 + wv] = s2; }
  __syncthreads();
  s  = red[0] + red[1] + red[2] + red[3];
  s2 = red[4] + red[5] + red[6] + red[7];
  const float mu  = s * (1.0f / EMBED);
  const float var = s2 * (1.0f / EMBED) - mu * mu;
  const float inv = rsqrtf(var + 1e-5f);
  float4 g  = *(const float4*)(gamma + tid * 4);
  float4 bt = *(const float4*)(beta + tid * 4);
  short4v o;
  o[0] = f2bf((v.x - mu) * inv * g.x + bt.x);
  o[1] = f2bf((v.y - mu) * inv * g.y + bt.y);
  o[2] = f2bf((v.z - mu) * inv * g.z + bt.z);
  o[3] = f2bf((v.w - mu) * inv * g.w + bt.w);
  *(short4v*)(xn + (size_t)row * EMBED + tid * 4) = o;
}

// ---------------- weight cast: 4 x 1M f32 -> bf16 ----------------
__global__ __launch_bounds__(256) void cast4_kernel(
    const float* __restrict__ a, const float* __restrict__ b,
    const float* __restrict__ c, const float* __restrict__ d,
    short* __restrict__ oa, short* __restrict__ ob,
    short* __restrict__ oc, short* __restrict__ od) {
  const int wsel = blockIdx.y;
  const float* s = (wsel == 0) ? a : (wsel == 1) ? b : (wsel == 2) ? c : d;
  short* o       = (wsel == 0) ? oa : (wsel == 1) ? ob : (wsel == 2) ? oc : od;
  const int i = (blockIdx.x * 256 + threadIdx.x) * 4;
  float4 v = *(const float4*)(s + i);
  short4v r;
  r[0] = f2bf(v.x); r[1] = f2bf(v.y); r[2] = f2bf(v.z); r[3] = f2bf(v.w);
  *(short4v*)(o + i) = r;
}

// ---------------- GEMM: C[M][1024] = A[M][1024] @ W^T + bias ----------------
// 128x128 tile, BK=32, 4 waves, prefetched double-buffer LDS (T3-min recipe).
// z==2 (V) writes output TRANSPOSED as [b][h][d][n] for the attention kernel.
template<bool F32OUT>
__global__ __launch_bounds__(256) void gemm_kernel(
    const short* __restrict__ A,
    const short* __restrict__ W0, const short* __restrict__ W1, const short* __restrict__ W2,
    const float* __restrict__ b0, const float* __restrict__ b1, const float* __restrict__ b2,
    void* __restrict__ O0, void* __restrict__ O1, void* __restrict__ O2) {
  constexpr int K = 1024, NOUT = 1024;
  const int z = blockIdx.z;
  const short* Bw   = (z == 0) ? W0 : (z == 1) ? W1 : W2;
  const float* bias = (z == 0) ? b0 : (z == 1) ? b1 : b2;
  void* Cout        = (z == 0) ? O0 : (z == 1) ? O1 : O2;

  const int tn = blockIdx.x, tm = blockIdx.y;
  const int tid = threadIdx.x, w = tid >> 6, lane = tid & 63;
  const int wm = w >> 1, wn = w & 1;
  const int g = lane >> 4, c = lane & 15;

  __shared__ short As[2][128 * 32];
  __shared__ short Bs[2][128 * 32];

  f32x4 acc[4][4];
#pragma unroll
  for (int i = 0; i < 4; i++)
#pragma unroll
    for (int j = 0; j < 4; j++) acc[i][j] = (f32x4){0.f, 0.f, 0.f, 0.f};

  const int crow = tid >> 2;   // 0..63
  const int ckc  = tid & 3;    // 0..3
  const short* ga = A  + (size_t)(tm * 128 + crow) * K + ckc * 8;
  const short* gb = Bw + (size_t)(tn * 128 + crow) * K + ckc * 8;

  auto STAGE = [&](int buf, int k0) {
    GLDS16(ga + k0,                   &As[buf][tid * 8]);
    GLDS16(ga + k0 + (size_t)64 * K,  &As[buf][tid * 8 + 64 * 32]);
    GLDS16(gb + k0,                   &Bs[buf][tid * 8]);
    GLDS16(gb + k0 + (size_t)64 * K,  &Bs[buf][tid * 8 + 64 * 32]);
  };

  STAGE(0, 0);
  __syncthreads();
  int cur = 0;
  for (int k0 = 0; k0 < K; k0 += 32) {
    if (k0 + 32 < K) STAGE(cur ^ 1, k0 + 32);
    short8 af[4], bfr[4];
#pragma unroll
    for (int mi = 0; mi < 4; mi++)
      af[mi] = *(const short8*)&As[cur][(wm * 64 + mi * 16 + c) * 32 + g * 8];
#pragma unroll
    for (int ni = 0; ni < 4; ni++)
      bfr[ni] = *(const short8*)&Bs[cur][(wn * 64 + ni * 16 + c) * 32 + g * 8];
#pragma unroll
    for (int mi = 0; mi < 4; mi++)
#pragma unroll
      for (int ni = 0; ni < 4; ni++)
        acc[mi][ni] = __builtin_amdgcn_mfma_f32_16x16x32_bf16(af[mi], bfr[ni], acc[mi][ni], 0, 0, 0);
    __syncthreads();
    cur ^= 1;
  }

  if (!F32OUT && z == 2) {
    // V: write transposed [b][h][d][n]
#pragma unroll
    for (int ni = 0; ni < 4; ni++) {
      const int col = tn * 128 + wn * 64 + ni * 16 + c;
      const float bs = bias[col];
      const int h2 = col >> 6, d = col & 63;
#pragma unroll
      for (int mi = 0; mi < 4; mi++) {
        const int row0 = tm * 128 + wm * 64 + mi * 16 + g * 4;
        const int bb = row0 >> 11, n0 = row0 & 2047;
        short4v o;
#pragma unroll
        for (int j = 0; j < 4; j++) o[j] = f2bf(acc[mi][ni][j] + bs);
        *(short4v*)&((short*)Cout)[((size_t)((bb << 4) + h2) * 64 + d) * 2048 + n0] = o;
      }
    }
  } else {
#pragma unroll
    for (int ni = 0; ni < 4; ni++) {
      const int col = tn * 128 + wn * 64 + ni * 16 + c;
      const float bs = bias[col];
#pragma unroll
      for (int mi = 0; mi < 4; mi++) {
#pragma unroll
        for (int j = 0; j < 4; j++) {
          const int row = tm * 128 + wm * 64 + mi * 16 + g * 4 + j;
          const float v = acc[mi][ni][j] + bs;
          if constexpr (F32OUT)
            ((float*)Cout)[(size_t)row * NOUT + col] = v;
          else
            ((short*)Cout)[(size_t)row * NOUT + col] = f2bf(v);
        }
      }
    }
  }
}

// ---------------- Flash attention: swapped QK^T, pre-transposed V, defer-max ----------------
// Grid: (32 q-tiles reversed, 32 b*h). 4 waves x 16 q-rows, KVBLK=64, dbuf LDS via global_load_lds.
__global__ __launch_bounds__(256) void attn_kernel(
    const short* __restrict__ Qm, const short* __restrict__ Km, const short* __restrict__ Vt,
    const float* __restrict__ relb, short* __restrict__ ctx) {
  const int qt = 31 - (int)blockIdx.x;
  const int bh = blockIdx.y;
  const int b = bh >> 4, h = bh & 15;
  const int tid = threadIdx.x, w = tid >> 6, lane = tid & 63;
  const int g = lane >> 4, c = lane & 15;
  constexpr float S31 = 31.0f / 2047.0f;

  __shared__ short k_lds[2][64 * 64];   // [m][d ^ ((m&7)<<3)] via pre-swizzled glds source
  __shared__ short vt_lds[2][64 * 64];  // [d][m ^ ((d&7)<<3)] via pre-swizzled glds source
  __shared__ short p_lds[4][16 * 64];   // per-wave P: [q=c][m ^ ((c&7)<<3)]
  __shared__ float rrow[64][33];        // bias pre-interpolated along q

  const int qbase = qt * 64;
  const size_t bhq = (size_t)b * NSEQ * EMBED + h * HDIM;
  const short* vtb = Vt + (size_t)((b << 4) + h) * 64 * 2048;

  // Q fragments: q-row = qbase + w*16 + c (MFMA B-operand of swapped QK^T)
  short8 qf[2];
  {
    const short* qp = Qm + bhq + (size_t)(qbase + w * 16 + c) * EMBED;
    qf[0] = *(const short8*)(qp + g * 8);
    qf[1] = *(const short8*)(qp + 32 + g * 8);
  }

  const int srow = tid >> 3;            // 0..31 (+32 second chunk)
  const int sd0  = (tid & 7) * 8;
  const int swz  = (srow & 7) << 3;

  // ---- prologue: stage tile 0 (K rows=m, Vt rows=d) ----
#pragma unroll
  for (int i = 0; i < 2; i++) {
    const int row = srow + i * 32;
    GLDS16(Km + bhq + (size_t)row * EMBED + (sd0 ^ swz), &k_lds[0][row * 64 + sd0]);
    GLDS16(vtb + (size_t)row * 2048 + (sd0 ^ swz),       &vt_lds[0][row * 64 + sd0]);
  }
  for (int i = tid; i < 64 * 32; i += 256) {
    const int qr = i >> 5, jj = i & 31;
    const int qg0 = qbase + qr;
    float rv = 0.f;
    if (qg0 != NSEQ - 1) {
      const float pos = qg0 * S31;
      const int i0 = (int)pos;
      const int i1 = min(i0 + 1, 31);
      const float fr = pos - (float)i0;
      const float* T = relb + h * 1024;
      rv = (1.f - fr) * T[i0 * 32 + jj] + fr * T[i1 * 32 + jj];
    }
    rrow[qr][jj] = rv;
  }
  __syncthreads();

  float mrow = -3.0e38f, lrow = 0.f;
  f32x4 oacc[4];
#pragma unroll
  for (int db = 0; db < 4; db++) oacc[db] = (f32x4){0.f, 0.f, 0.f, 0.f};

  const int qg = qbase + w * 16 + c;
  const float* rr = &rrow[w * 16 + c][0];
  const int csw = (c & 7) << 3;
  const int nkv = qt + 1;

  for (int kt = 0; kt < nkv; kt++) {
    const int cur = kt & 1;
    const int kv0 = kt * 64;
    const short* kl = &k_lds[cur][0];
    const short* vl = &vt_lds[cur][0];

    if (kt + 1 < nkv) {
#pragma unroll
      for (int i = 0; i < 2; i++) {
        const int row = srow + i * 32;
        GLDS16(Km + bhq + (size_t)(kv0 + 64 + row) * EMBED + (sd0 ^ swz),
               &k_lds[cur ^ 1][row * 64 + sd0]);
        GLDS16(vtb + (size_t)row * 2048 + (kv0 + 64) + (sd0 ^ swz),
               &vt_lds[cur ^ 1][row * 64 + sd0]);
      }
    }

    // S^T = K Q^T : lane (g,c) gets S[q=c][m = mb*16 + g*4 + j]
    f32x4 st[4];
#pragma unroll
    for (int mb = 0; mb < 4; mb++) st[mb] = (f32x4){0.f, 0.f, 0.f, 0.f};
    __builtin_amdgcn_s_setprio(1);
#pragma unroll
    for (int kh = 0; kh < 2; kh++) {
      const int dk = kh * 32 + g * 8;
#pragma unroll
      for (int mb = 0; mb < 4; mb++) {
        const int row = mb * 16 + c;
        short8 kf = *(const short8*)&kl[row * 64 + (dk ^ ((row & 7) << 3))];
        st[mb] = __builtin_amdgcn_mfma_f32_16x16x32_bf16(kf, qf[kh], st[mb], 0, 0, 0);
      }
    }
    __builtin_amdgcn_s_setprio(0);

    // scale + rel bias (segment-select, 3 LDS reads/tile) + causal mask
    float p[4][4];
    float pmax = -3.0e38f;
    const bool diag = (kt == qt);
    const int I = (int)(kv0 * S31);
    const float rA = rr[I];
    const float rB = rr[I + 1];
    const float rC = rr[min(I + 2, 31)];
    const float dAB = rB - rA, dBC = rC - rB;
#pragma unroll
    for (int mb = 0; mb < 4; mb++) {
#pragma unroll
      for (int j = 0; j < 4; j++) {
        const int mg = kv0 + mb * 16 + g * 4 + j;
        const float pos = mg * S31;
        const int i0 = (int)pos;
        const float fr = pos - (float)i0;
        const bool sel = i0 > I;
        float sv = st[mb][j] * 0.125f;
        if (mg != NSEQ - 1) sv += fmaf(fr, sel ? dBC : dAB, sel ? rB : rA);
        if (diag && mg > qg) sv = -3.0e38f;
        p[mb][j] = sv;
        pmax = fmaxf(pmax, sv);
      }
    }
    pmax = fmaxf(pmax, __shfl_xor(pmax, 16));
    pmax = fmaxf(pmax, __shfl_xor(pmax, 32));

    if (!__all(pmax - mrow <= 8.0f)) {       // defer-max
      const float mnew = fmaxf(mrow, pmax);
      const float al = __expf(mrow - mnew);
      mrow = mnew;
      lrow *= al;
      float alj[4];
#pragma unroll
      for (int j = 0; j < 4; j++) alj[j] = __shfl(al, g * 4 + j);
#pragma unroll
      for (int db = 0; db < 4; db++)
#pragma unroll
        for (int j = 0; j < 4; j++) oacc[db][j] *= alj[j];
    }

    float rs = 0.f;
#pragma unroll
    for (int mb = 0; mb < 4; mb++)
#pragma unroll
      for (int j = 0; j < 4; j++) {
        const float pe = __expf(p[mb][j] - mrow);
        p[mb][j] = pe;
        rs += pe;
      }
    rs += __shfl_xor(rs, 16);
    rs += __shfl_xor(rs, 32);
    lrow += rs;

    // P -> p_lds (bf16 pairs, swizzled), wave-local
    short* pw = &p_lds[w][0];
#pragma unroll
    for (int mb = 0; mb < 4; mb++)
#pragma unroll
      for (int jh = 0; jh < 2; jh++) {
        const int m = mb * 16 + g * 4 + jh * 2;
        unsigned int pk = ((unsigned int)(unsigned short)f2bf(p[mb][jh * 2 + 1]) << 16)
                        |  (unsigned int)(unsigned short)f2bf(p[mb][jh * 2]);
        *(unsigned int*)&pw[c * 64 + (m ^ csw)] = pk;
      }

    // O += P V  (B-operand: contiguous swizzled b128 from transposed V tile)
    __builtin_amdgcn_s_setprio(1);
#pragma unroll
    for (int kb = 0; kb < 2; kb++) {
      const int m0 = kb * 32 + g * 8;
      short8 pa = *(const short8*)&pw[c * 64 + (m0 ^ csw)];
#pragma unroll
      for (int db = 0; db < 4; db++) {
        const int d = db * 16 + c;
        short8 vf = *(const short8*)&vl[d * 64 + (m0 ^ ((d & 7) << 3))];
        oacc[db] = __builtin_amdgcn_mfma_f32_16x16x32_bf16(pa, vf, oacc[db], 0, 0, 0);
      }
    }
    __builtin_amdgcn_s_setprio(0);
    __syncthreads();
  }

  // epilogue: redistribute l to D-domain rows, normalize, store
  float linv[4];
#pragma unroll
  for (int j = 0; j < 4; j++) linv[j] = 1.f / __shfl(lrow, g * 4 + j);
#pragma unroll
  for (int j = 0; j < 4; j++) {
    short* op = ctx + bhq + (size_t)(qbase + w * 16 + g * 4 + j) * EMBED;
#pragma unroll
    for (int db = 0; db < 4; db++)
      op[db * 16 + c] = f2bf(oacc[db][j] * linv[j]);
  }
}

extern "C" void kernel_launch(void* const* d_in, const int* in_sizes, int n_in,
                              void* d_out, int out_size, void* d_ws, size_t ws_size,
                              hipStream_t stream) {
  const float* x     = (const float*)d_in[0];
  const float* Wq    = (const float*)d_in[1];
  const float* bq    = (const float*)d_in[2];
  const float* Wk    = (const float*)d_in[3];
  const float* bk    = (const float*)d_in[4];
  const float* Wv    = (const float*)d_in[5];
  const float* bv    = (const float*)d_in[6];
  const float* Wo    = (const float*)d_in[7];
  const float* bo    = (const float*)d_in[8];
  const float* gamma = (const float*)d_in[9];
  const float* beta  = (const float*)d_in[10];
  const float* relb  = (const float*)d_in[11];
  float* out = (float*)d_out;

  char* ws = (char*)d_ws;
  short* xn  = (short*)ws; ws += (size_t)NTOK * EMBED * 2;
  short* wqb = (short*)ws; ws += (size_t)EMBED * EMBED * 2;
  short* wkb = (short*)ws; ws += (size_t)EMBED * EMBED * 2;
  short* wvb = (short*)ws; ws += (size_t)EMBED * EMBED * 2;
  short* wob = (short*)ws; ws += (size_t)EMBED * EMBED * 2;
  short* qb  = (short*)ws; ws += (size_t)NTOK * EMBED * 2;
  short* kb_ = (short*)ws; ws += (size_t)NTOK * EMBED * 2;
  short* vtb = (short*)ws; ws += (size_t)NTOK * EMBED * 2;   // V transposed [b][h][d][n]
  short* ctx = (short*)ws; ws += (size_t)NTOK * EMBED * 2;

  ln_kernel<<<dim3(NTOK), dim3(256), 0, stream>>>(x, gamma, beta, xn);
  cast4_kernel<<<dim3(1024, 4), dim3(256), 0, stream>>>(Wq, Wk, Wv, Wo, wqb, wkb, wvb, wob);
  gemm_kernel<false><<<dim3(8, 32, 3), dim3(256), 0, stream>>>(
      xn, wqb, wkb, wvb, bq, bk, bv, (void*)qb, (void*)kb_, (void*)vtb);
  attn_kernel<<<dim3(32, 32), dim3(256), 0, stream>>>(qb, kb_, vtb, relb, ctx);
  gemm_kernel<true><<<dim3(8, 32, 1), dim3(256), 0, stream>>>(
      ctx, wob, wob, wob, bo, bo, bo, (void*)out, (void*)out, (void*)out);
}

// Round 4
// 234.839 us; speedup vs baseline: 1.3610x; 1.2461x over previous
//
#include <hip/hip_runtime.h>
#include <hip/hip_bf16.h>

#define EMBED 1024
#define NHEADS 16
#define HDIM 64
#define NB 2
#define NSEQ 2048
#define NTOK (NB*NSEQ)   // 4096

using short8  = __attribute__((ext_vector_type(8))) short;
using short4v = __attribute__((ext_vector_type(4))) short;
using f32x4   = __attribute__((ext_vector_type(4))) float;

#define INV_LN2 1.4426950408889634f

__device__ __forceinline__ short f2bf(float x) {
  __hip_bfloat16 h = __float2bfloat16(x);
  short s;
  __builtin_memcpy(&s, &h, 2);
  return s;
}

#define GLDS16(gp, lp) __builtin_amdgcn_global_load_lds( \
    (const __attribute__((address_space(1))) unsigned int*)(const void*)(gp), \
    (__attribute__((address_space(3))) unsigned int*)(void*)(lp), 16, 0, 0)

// ---------------- LayerNorm: f32 [4096][1024] -> bf16 xn ----------------
__global__ __launch_bounds__(256) void ln_kernel(const float* __restrict__ x,
    const float* __restrict__ gamma, const float* __restrict__ beta,
    short* __restrict__ xn) {
  const int row = blockIdx.x;
  const int tid = threadIdx.x;
  const float* xr = x + (size_t)row * EMBED;
  float4 v = *(const float4*)(xr + tid * 4);
  float s  = v.x + v.y + v.z + v.w;
  float s2 = v.x*v.x + v.y*v.y + v.z*v.z + v.w*v.w;
#pragma unroll
  for (int off = 32; off; off >>= 1) {
    s  += __shfl_down(s, off);
    s2 += __shfl_down(s2, off);
  }
  __shared__ float red[8];
  const int wv = tid >> 6, ln = tid & 63;
  if (ln == 0) { red[wv] = s; red[4 + wv] = s2; }
  __syncthreads();
  s  = red[0] + red[1] + red[2] + red[3];
  s2 = red[4] + red[5] + red[6] + red[7];
  const float mu  = s * (1.0f / EMBED);
  const float var = s2 * (1.0f / EMBED) - mu * mu;
  const float inv = rsqrtf(var + 1e-5f);
  float4 g  = *(const float4*)(gamma + tid * 4);
  float4 bt = *(const float4*)(beta + tid * 4);
  short4v o;
  o[0] = f2bf((v.x - mu) * inv * g.x + bt.x);
  o[1] = f2bf((v.y - mu) * inv * g.y + bt.y);
  o[2] = f2bf((v.z - mu) * inv * g.z + bt.z);
  o[3] = f2bf((v.w - mu) * inv * g.w + bt.w);
  *(short4v*)(xn + (size_t)row * EMBED + tid * 4) = o;
}

// ---------------- weight cast: 4 x 1M f32 -> bf16 ----------------
__global__ __launch_bounds__(256) void cast4_kernel(
    const float* __restrict__ a, const float* __restrict__ b,
    const float* __restrict__ c, const float* __restrict__ d,
    short* __restrict__ oa, short* __restrict__ ob,
    short* __restrict__ oc, short* __restrict__ od) {
  const int wsel = blockIdx.y;
  const float* s = (wsel == 0) ? a : (wsel == 1) ? b : (wsel == 2) ? c : d;
  short* o       = (wsel == 0) ? oa : (wsel == 1) ? ob : (wsel == 2) ? oc : od;
  const int i = (blockIdx.x * 256 + threadIdx.x) * 4;
  float4 v = *(const float4*)(s + i);
  short4v r;
  r[0] = f2bf(v.x); r[1] = f2bf(v.y); r[2] = f2bf(v.z); r[3] = f2bf(v.w);
  *(short4v*)(o + i) = r;
}

// ---------------- GEMM: C[M][1024] = A[M][1024] @ W^T + bias ----------------
// 128x128 tile, BK=32, 4 waves, global_load_lds staging (m97 structure).
template<bool F32OUT>
__global__ __launch_bounds__(256) void gemm_kernel(
    const short* __restrict__ A,
    const short* __restrict__ W0, const short* __restrict__ W1, const short* __restrict__ W2,
    const float* __restrict__ b0, const float* __restrict__ b1, const float* __restrict__ b2,
    void* __restrict__ O0, void* __restrict__ O1, void* __restrict__ O2) {
  constexpr int K = 1024, NOUT = 1024;
  const int z = blockIdx.z;
  const short* Bw   = (z == 0) ? W0 : (z == 1) ? W1 : W2;
  const float* bias = (z == 0) ? b0 : (z == 1) ? b1 : b2;
  void* Cout        = (z == 0) ? O0 : (z == 1) ? O1 : O2;

  const int tn = blockIdx.x, tm = blockIdx.y;
  const int tid = threadIdx.x, w = tid >> 6, lane = tid & 63;
  const int wm = w >> 1, wn = w & 1;
  const int g = lane >> 4, c = lane & 15;

  __shared__ short As[128 * 32];
  __shared__ short Bs[128 * 32];

  f32x4 acc[4][4];
#pragma unroll
  for (int i = 0; i < 4; i++)
#pragma unroll
    for (int j = 0; j < 4; j++) acc[i][j] = (f32x4){0.f, 0.f, 0.f, 0.f};

  const int crow = tid >> 2;   // 0..63
  const int ckc  = tid & 3;    // 0..3
  const short* ga = A  + (size_t)(tm * 128 + crow) * K + ckc * 8;
  const short* gb = Bw + (size_t)(tn * 128 + crow) * K + ckc * 8;
  short* la = &As[tid * 8];
  short* lb = &Bs[tid * 8];

  for (int k0 = 0; k0 < K; k0 += 32) {
    __syncthreads();
    GLDS16(ga + k0, la);
    GLDS16(ga + k0 + (size_t)64 * K, la + 64 * 32);
    GLDS16(gb + k0, lb);
    GLDS16(gb + k0 + (size_t)64 * K, lb + 64 * 32);
    __syncthreads();
    short8 af[4], bfr[4];
#pragma unroll
    for (int mi = 0; mi < 4; mi++)
      af[mi] = *(const short8*)&As[(wm * 64 + mi * 16 + c) * 32 + g * 8];
#pragma unroll
    for (int ni = 0; ni < 4; ni++)
      bfr[ni] = *(const short8*)&Bs[(wn * 64 + ni * 16 + c) * 32 + g * 8];
#pragma unroll
    for (int mi = 0; mi < 4; mi++)
#pragma unroll
      for (int ni = 0; ni < 4; ni++)
        acc[mi][ni] = __builtin_amdgcn_mfma_f32_16x16x32_bf16(af[mi], bfr[ni], acc[mi][ni], 0, 0, 0);
  }

#pragma unroll
  for (int ni = 0; ni < 4; ni++) {
    const int col = tn * 128 + wn * 64 + ni * 16 + c;
    const float bs = bias[col];
#pragma unroll
    for (int mi = 0; mi < 4; mi++) {
#pragma unroll
      for (int j = 0; j < 4; j++) {
        const int row = tm * 128 + wm * 64 + mi * 16 + g * 4 + j;
        const float v = acc[mi][ni][j] + bs;
        if constexpr (F32OUT)
          ((float*)Cout)[(size_t)row * NOUT + col] = v;
        else
          ((short*)Cout)[(size_t)row * NOUT + col] = f2bf(v);
      }
    }
  }
}

// ---------------- V transpose: [n][h*64+d] -> [b][h][d][n(2048)] ----------------
__global__ __launch_bounds__(256) void vtrans_kernel(const short* __restrict__ vb,
                                                     short* __restrict__ vt) {
  const int n0 = blockIdx.x * 64;
  const int bh = blockIdx.y;
  const int b = bh >> 4, h = bh & 15;
  const int tid = threadIdx.x;
  __shared__ short tl[64 * 68];   // [n][d], pad 68

  const int r  = tid >> 3;        // 0..31
  const int c8 = (tid & 7) * 8;
#pragma unroll
  for (int i = 0; i < 2; i++) {
    const int row = r + i * 32;
    short8 v = *(const short8*)(vb + (size_t)(b * NSEQ + n0 + row) * EMBED + h * 64 + c8);
    *(short8*)&tl[row * 68 + c8] = v;
  }
  __syncthreads();
  const int d  = tid >> 2;        // 0..63
  const int ns = (tid & 3) * 16;
  short8 o0, o1;
#pragma unroll
  for (int e = 0; e < 8; e++) {
    o0[e] = tl[(ns + e) * 68 + d];
    o1[e] = tl[(ns + 8 + e) * 68 + d];
  }
  short* dst = vt + ((size_t)((b * 16 + h) * 64 + d)) * 2048 + n0 + ns;
  *(short8*)dst = o0;
  *(short8*)(dst + 8) = o1;
}

// ---------------- Flash attention: 8 waves x 16 q-rows (128 rows/block) ----------------
// Grid: 512 blocks 1D; qpair mapping balances co-resident block pairs.
__global__ __launch_bounds__(512, 4) void attn_kernel(
    const short* __restrict__ Qm, const short* __restrict__ Km, const short* __restrict__ Vt,
    const float* __restrict__ relb, short* __restrict__ ctx) {
  const int bid = blockIdx.x;
  const int bh  = bid & 31;
  const int idx = bid >> 5;                       // 0..15
  const int qpair = (idx < 8) ? (15 - idx) : (idx - 8);
  const int b = bh >> 4, h = bh & 15;
  const int tid = threadIdx.x, w = tid >> 6, lane = tid & 63;
  const int g = lane >> 4, c = lane & 15;
  constexpr float S31 = 31.0f / 2047.0f;

  __shared__ short k_lds[2][64 * 64];   // [m][d ^ ((m&7)<<3)] via pre-swizzled glds source
  __shared__ short vt_lds[2][64 * 64];  // [d][m ^ ((d&7)<<3)] via pre-swizzled glds source
  __shared__ short p_lds[8][16 * 64];   // per-wave P: [q=c][m ^ ((c&7)<<3)]
  __shared__ float rrow[128][33];       // bias pre-interpolated along q (log2 units)

  const int qbase = qpair * 128;
  const size_t bhq = (size_t)b * NSEQ * EMBED + h * HDIM;
  const short* vtb = Vt + (size_t)((b << 4) + h) * 64 * 2048;

  // Q fragments: q-row = qbase + w*16 + c (MFMA B-operand of swapped QK^T)
  short8 qf[2];
  {
    const short* qp = Qm + bhq + (size_t)(qbase + w * 16 + c) * EMBED;
    qf[0] = *(const short8*)(qp + g * 8);
    qf[1] = *(const short8*)(qp + 32 + g * 8);
  }

  const int srow = tid >> 3;            // 0..63
  const int sd0  = (tid & 7) * 8;
  const int swz  = (srow & 7) << 3;

  // ---- prologue: stage tile 0 ----
  GLDS16(Km + bhq + (size_t)srow * EMBED + (sd0 ^ swz), &k_lds[0][srow * 64 + sd0]);
  GLDS16(vtb + (size_t)srow * 2048 + (sd0 ^ swz),       &vt_lds[0][srow * 64 + sd0]);
  for (int i = tid; i < 128 * 32; i += 512) {
    const int qr = i >> 5, jj = i & 31;
    const int qg0 = qbase + qr;
    float rv = 0.f;
    if (qg0 != NSEQ - 1) {
      const float pos = qg0 * S31;
      const int i0 = (int)pos;
      const int i1 = min(i0 + 1, 31);
      const float fr = pos - (float)i0;
      const float* T = relb + h * 1024;
      rv = ((1.f - fr) * T[i0 * 32 + jj] + fr * T[i1 * 32 + jj]) * INV_LN2;
    }
    rrow[qr][jj] = rv;
  }
  __syncthreads();

  float mrow = -3.0e38f, lrow = 0.f;
  f32x4 oacc[4];
#pragma unroll
  for (int db = 0; db < 4; db++) oacc[db] = (f32x4){0.f, 0.f, 0.f, 0.f};

  const int qg  = qbase + w * 16 + c;
  const int qhi = qbase + w * 16 + 15;           // wave-uniform
  const float* rr = &rrow[w * 16 + c][0];
  const int csw = (c & 7) << 3;
  const int nkv = 2 * qpair + 2;

  for (int kt = 0; kt < nkv; kt++) {
    const int cur = kt & 1;
    const int kv0 = kt * 64;

    if (kt + 1 < nkv) {
      GLDS16(Km + bhq + (size_t)(kv0 + 64 + srow) * EMBED + (sd0 ^ swz),
             &k_lds[cur ^ 1][srow * 64 + sd0]);
      GLDS16(vtb + (size_t)srow * 2048 + (kv0 + 64) + (sd0 ^ swz),
             &vt_lds[cur ^ 1][srow * 64 + sd0]);
    }

    if (kv0 <= qhi) {                            // wave-active (causal skip)
      const short* kl = &k_lds[cur][0];
      const short* vl = &vt_lds[cur][0];

      // S^T = K Q^T : lane (g,c) gets S[q=c][m = mb*16 + g*4 + j]
      f32x4 st[4];
#pragma unroll
      for (int mb = 0; mb < 4; mb++) st[mb] = (f32x4){0.f, 0.f, 0.f, 0.f};
      __builtin_amdgcn_s_setprio(1);
#pragma unroll
      for (int kh = 0; kh < 2; kh++) {
        const int dk = kh * 32 + g * 8;
#pragma unroll
        for (int mb = 0; mb < 4; mb++) {
          const int row = mb * 16 + c;
          short8 kf = *(const short8*)&kl[row * 64 + (dk ^ ((row & 7) << 3))];
          st[mb] = __builtin_amdgcn_mfma_f32_16x16x32_bf16(kf, qf[kh], st[mb], 0, 0, 0);
        }
      }
      __builtin_amdgcn_s_setprio(0);

      // scale (log2 domain) + rel bias + causal mask
      float p[4][4];
      float pmax = -3.0e38f;
      const bool diag = (kv0 + 63 > qg);
      const int I = (int)(kv0 * S31);
      const float rA = rr[I];
      const float rB = rr[I + 1];
      const float rC = rr[min(I + 2, 31)];
      const float dAB = rB - rA, dBC = rC - rB;
#pragma unroll
      for (int mb = 0; mb < 4; mb++) {
#pragma unroll
        for (int j = 0; j < 4; j++) {
          const int mg = kv0 + mb * 16 + g * 4 + j;
          const float pos = mg * S31;
          const int i0 = (int)pos;
          const float fr = pos - (float)i0;
          const bool sel = i0 > I;
          float sv = st[mb][j] * (0.125f * INV_LN2);
          if (mg != NSEQ - 1) sv += fmaf(fr, sel ? dBC : dAB, sel ? rB : rA);
          if (diag && mg > qg) sv = -3.0e38f;
          p[mb][j] = sv;
          pmax = fmaxf(pmax, sv);
        }
      }
      pmax = fmaxf(pmax, __shfl_xor(pmax, 16));
      pmax = fmaxf(pmax, __shfl_xor(pmax, 32));

      if (!__all(pmax - mrow <= 11.6f)) {        // defer-max (log2 units)
        const float mnew = fmaxf(mrow, pmax);
        const float al = exp2f(mrow - mnew);
        mrow = mnew;
        lrow *= al;
        float alj[4];
#pragma unroll
        for (int j = 0; j < 4; j++) alj[j] = __shfl(al, g * 4 + j);
#pragma unroll
        for (int db = 0; db < 4; db++)
#pragma unroll
          for (int j = 0; j < 4; j++) oacc[db][j] *= alj[j];
      }

      float rs = 0.f;
#pragma unroll
      for (int mb = 0; mb < 4; mb++)
#pragma unroll
        for (int j = 0; j < 4; j++) {
          const float pe = exp2f(p[mb][j] - mrow);
          p[mb][j] = pe;
          rs += pe;
        }
      rs += __shfl_xor(rs, 16);
      rs += __shfl_xor(rs, 32);
      lrow += rs;

      // P -> p_lds (bf16 pairs, swizzled), wave-local
      short* pw = &p_lds[w][0];
#pragma unroll
      for (int mb = 0; mb < 4; mb++)
#pragma unroll
        for (int jh = 0; jh < 2; jh++) {
          const int m = mb * 16 + g * 4 + jh * 2;
          unsigned int pk = ((unsigned int)(unsigned short)f2bf(p[mb][jh * 2 + 1]) << 16)
                          |  (unsigned int)(unsigned short)f2bf(p[mb][jh * 2]);
          *(unsigned int*)&pw[c * 64 + (m ^ csw)] = pk;
        }

      // O += P V
      __builtin_amdgcn_s_setprio(1);
#pragma unroll
      for (int kb = 0; kb < 2; kb++) {
        const int m0 = kb * 32 + g * 8;
        short8 pa = *(const short8*)&pw[c * 64 + (m0 ^ csw)];
#pragma unroll
        for (int db = 0; db < 4; db++) {
          const int d = db * 16 + c;
          short8 vf = *(const short8*)&vl[d * 64 + (m0 ^ ((d & 7) << 3))];
          oacc[db] = __builtin_amdgcn_mfma_f32_16x16x32_bf16(pa, vf, oacc[db], 0, 0, 0);
        }
      }
      __builtin_amdgcn_s_setprio(0);
    }
    __syncthreads();
  }

  // epilogue: redistribute l to D-domain rows, normalize, store
  float linv[4];
#pragma unroll
  for (int j = 0; j < 4; j++) linv[j] = 1.f / __shfl(lrow, g * 4 + j);
#pragma unroll
  for (int j = 0; j < 4; j++) {
    short* op = ctx + bhq + (size_t)(qbase + w * 16 + g * 4 + j) * EMBED;
#pragma unroll
    for (int db = 0; db < 4; db++)
      op[db * 16 + c] = f2bf(oacc[db][j] * linv[j]);
  }
}

extern "C" void kernel_launch(void* const* d_in, const int* in_sizes, int n_in,
                              void* d_out, int out_size, void* d_ws, size_t ws_size,
                              hipStream_t stream) {
  const float* x     = (const float*)d_in[0];
  const float* Wq    = (const float*)d_in[1];
  const float* bq    = (const float*)d_in[2];
  const float* Wk    = (const float*)d_in[3];
  const float* bk    = (const float*)d_in[4];
  const float* Wv    = (const float*)d_in[5];
  const float* bv    = (const float*)d_in[6];
  const float* Wo    = (const float*)d_in[7];
  const float* bo    = (const float*)d_in[8];
  const float* gamma = (const float*)d_in[9];
  const float* beta  = (const float*)d_in[10];
  const float* relb  = (const float*)d_in[11];
  float* out = (float*)d_out;

  char* ws = (char*)d_ws;
  short* xn  = (short*)ws; ws += (size_t)NTOK * EMBED * 2;   // reused as vtb after QKV GEMM
  short* wqb = (short*)ws; ws += (size_t)EMBED * EMBED * 2;
  short* wkb = (short*)ws; ws += (size_t)EMBED * EMBED * 2;
  short* wvb = (short*)ws; ws += (size_t)EMBED * EMBED * 2;
  short* wob = (short*)ws; ws += (size_t)EMBED * EMBED * 2;
  short* qb  = (short*)ws; ws += (size_t)NTOK * EMBED * 2;
  short* kb_ = (short*)ws; ws += (size_t)NTOK * EMBED * 2;
  short* vb  = (short*)ws; ws += (size_t)NTOK * EMBED * 2;   // V normal layout
  short* ctx = (short*)ws; ws += (size_t)NTOK * EMBED * 2;
  short* vtb = xn;                                           // V transposed [b][h][d][n]

  ln_kernel<<<dim3(NTOK), dim3(256), 0, stream>>>(x, gamma, beta, xn);
  cast4_kernel<<<dim3(1024, 4), dim3(256), 0, stream>>>(Wq, Wk, Wv, Wo, wqb, wkb, wvb, wob);
  gemm_kernel<false><<<dim3(8, 32, 3), dim3(256), 0, stream>>>(
      xn, wqb, wkb, wvb, bq, bk, bv, (void*)qb, (void*)kb_, (void*)vb);
  vtrans_kernel<<<dim3(32, 32), dim3(256), 0, stream>>>(vb, vtb);
  attn_kernel<<<dim3(512), dim3(512), 0, stream>>>(qb, kb_, vtb, relb, ctx);
  gemm_kernel<true><<<dim3(8, 32, 1), dim3(256), 0, stream>>>(
      ctx, wob, wob, wob, bo, bo, bo, (void*)out, (void*)out, (void*)out);
}